// Round 1
// baseline (87.372 us; speedup 1.0000x reference)
//
#include <hip/hip_runtime.h>
#include <math.h>

// RBF kernel matrix: cov[i][j] = exp(-0.5 * sum_d ((x[i,d]-xx[j,d])*inv_scale[d])^2 + log_var)
// N=M=4096, D=8. Write-BW bound: 67 MB fp32 output.

constexpr int D   = 8;   // feature dim (fixed by reference)
constexpr int TJ  = 4;   // columns per thread  -> one float4 store
constexpr int TI  = 8;   // rows per block      -> amortize xx register load
constexpr int BLK = 256; // threads per block

__global__ __launch_bounds__(BLK) void rbf_kernel(
    const float* __restrict__ x,         // [N, D]
    const float* __restrict__ xx,        // [M, D]
    const float* __restrict__ log_scale, // [D]
    const float* __restrict__ log_var,   // [1]
    float* __restrict__ out,             // [N, M]
    int N, int M)
{
    const int jbase = (blockIdx.x * BLK + threadIdx.x) * TJ;
    const int ibase = blockIdx.y * TI;
    if (jbase >= M) return;

    // inv_scale[d] = exp(-log_scale[d]); fold variance into the exponent.
    float inv[D];
#pragma unroll
    for (int d = 0; d < D; ++d) inv[d] = __expf(-log_scale[d]);
    const float lv = log_var[0];

    // Load this thread's 4 xx rows into registers, pre-scaled.
    float xxv[TJ][D];
#pragma unroll
    for (int jj = 0; jj < TJ; ++jj) {
        const float4* p = (const float4*)(xx + (size_t)(jbase + jj) * D);
        float4 a = p[0], b = p[1];
        xxv[jj][0] = a.x * inv[0]; xxv[jj][1] = a.y * inv[1];
        xxv[jj][2] = a.z * inv[2]; xxv[jj][3] = a.w * inv[3];
        xxv[jj][4] = b.x * inv[4]; xxv[jj][5] = b.y * inv[5];
        xxv[jj][6] = b.z * inv[6]; xxv[jj][7] = b.w * inv[7];
    }

#pragma unroll
    for (int r = 0; r < TI; ++r) {
        const int i = ibase + r;
        if (i >= N) break;
        // x-row load is wave-uniform -> one L1 broadcast fetch.
        const float4* px = (const float4*)(x + (size_t)i * D);
        float4 a = px[0], b = px[1];
        float xs[D];
        xs[0] = a.x * inv[0]; xs[1] = a.y * inv[1];
        xs[2] = a.z * inv[2]; xs[3] = a.w * inv[3];
        xs[4] = b.x * inv[4]; xs[5] = b.y * inv[5];
        xs[6] = b.z * inv[6]; xs[7] = b.w * inv[7];

        float res[TJ];
#pragma unroll
        for (int jj = 0; jj < TJ; ++jj) {
            float acc = 0.f;
#pragma unroll
            for (int d = 0; d < D; ++d) {
                const float t = xs[d] - xxv[jj][d];
                acc = fmaf(t, t, acc);
            }
            res[jj] = __expf(fmaf(-0.5f, acc, lv));
        }
        float4 o = { res[0], res[1], res[2], res[3] };
        *(float4*)(out + (size_t)i * M + jbase) = o;
    }
}

extern "C" void kernel_launch(void* const* d_in, const int* in_sizes, int n_in,
                              void* d_out, int out_size, void* d_ws, size_t ws_size,
                              hipStream_t stream) {
    const float* x   = (const float*)d_in[0];
    const float* xx  = (const float*)d_in[1];
    const float* ls  = (const float*)d_in[2];
    const float* lv  = (const float*)d_in[3];
    float* out       = (float*)d_out;

    const int N = in_sizes[0] / D;
    const int M = in_sizes[1] / D;

    dim3 block(BLK, 1, 1);
    dim3 grid((M + BLK * TJ - 1) / (BLK * TJ), (N + TI - 1) / TI, 1);
    rbf_kernel<<<grid, block, 0, stream>>>(x, xx, ls, lv, out, N, M);
}

// Round 2
// 85.862 us; speedup vs baseline: 1.0176x; 1.0176x over previous
//
#include <hip/hip_runtime.h>
#include <math.h>

// RBF kernel matrix: cov[i][j] = exp(lv - 0.5*||(x_i - xx_j) * inv_scale||^2)
// Expanded form: exponent = h_i + c_j + sum_d x[i,d] * B[j,d]
//   w[d]    = inv_scale[d]^2
//   B[j,d]  = xx[j,d] * w[d]
//   c[j]    = lv - 0.5 * sum_d xx[j,d]^2 * w[d]
//   h_i     = -0.5 * sum_d x[i,d]^2 * w[d]
// Per output: 8 FMA + 1 add + 1 exp. Write-BW bound: 67 MB fp32 out.

constexpr int D   = 8;   // feature dim (fixed by reference)
constexpr int TJ  = 4;   // columns per thread  -> one float4 store
constexpr int TI  = 8;   // rows per block      -> amortize column precompute
constexpr int BLK = 256; // threads per block

__global__ __launch_bounds__(BLK) void rbf_kernel(
    const float* __restrict__ x,         // [N, D]
    const float* __restrict__ xx,        // [M, D]
    const float* __restrict__ log_scale, // [D]
    const float* __restrict__ log_var,   // [1]
    float* __restrict__ out,             // [N, M]
    int N, int M)
{
    const int j0 = (blockIdx.x * BLK + threadIdx.x) * TJ;
    const int i0 = blockIdx.y * TI;
    if (j0 + TJ > M || i0 + TI > N) return;  // exact grid for 4096; safety only

    float w[D];
#pragma unroll
    for (int d = 0; d < D; ++d) {
        const float s = __expf(-log_scale[d]);  // 1/scale
        w[d] = s * s;
    }
    const float lv = log_var[0];

    // Per-column precompute (registers): B[jj][d], c[jj]
    float B[TJ][D], c[TJ];
#pragma unroll
    for (int jj = 0; jj < TJ; ++jj) {
        const float4* p = (const float4*)(xx + (size_t)(j0 + jj) * D);
        const float4 a = p[0], b = p[1];
        const float v[D] = {a.x, a.y, a.z, a.w, b.x, b.y, b.z, b.w};
        float q = 0.f;
#pragma unroll
        for (int d = 0; d < D; ++d) {
            B[jj][d] = v[d] * w[d];
            q = fmaf(v[d], B[jj][d], q);       // sum xx^2 * w
        }
        c[jj] = fmaf(-0.5f, q, lv);
    }

#pragma unroll
    for (int r = 0; r < TI; ++r) {
        const int i = i0 + r;
        // x-row address is wave-uniform -> scalar/broadcast fetch, L1/L2-hot.
        const float4* px = (const float4*)(x + (size_t)i * D);
        const float4 a = px[0], b = px[1];
        const float v[D] = {a.x, a.y, a.z, a.w, b.x, b.y, b.z, b.w};
        float q = 0.f;
#pragma unroll
        for (int d = 0; d < D; ++d) q = fmaf(v[d] * w[d], v[d], q);
        const float h = -0.5f * q;

        float res[TJ];
#pragma unroll
        for (int jj = 0; jj < TJ; ++jj) {
            float e = h + c[jj];
#pragma unroll
            for (int d = 0; d < D; ++d) e = fmaf(v[d], B[jj][d], e);
            res[jj] = __expf(e);
        }
        const float4 o = {res[0], res[1], res[2], res[3]};
        *(float4*)(out + (size_t)i * M + j0) = o;
    }
}

extern "C" void kernel_launch(void* const* d_in, const int* in_sizes, int n_in,
                              void* d_out, int out_size, void* d_ws, size_t ws_size,
                              hipStream_t stream) {
    const float* x  = (const float*)d_in[0];
    const float* xx = (const float*)d_in[1];
    const float* ls = (const float*)d_in[2];
    const float* lv = (const float*)d_in[3];
    float* out      = (float*)d_out;

    const int N = in_sizes[0] / D;
    const int M = in_sizes[1] / D;

    dim3 block(BLK, 1, 1);
    dim3 grid((M + BLK * TJ - 1) / (BLK * TJ), (N + TI - 1) / TI, 1);
    rbf_kernel<<<grid, block, 0, stream>>>(x, xx, ls, lv, out, N, M);
}